// Round 8
// baseline (180.077 us; speedup 1.0000x reference)
//
#include <hip/hip_runtime.h>
#include <math.h>

// ---------------- problem constants ----------------
#define NB      32
#define NPTS    8192
#define TOTPTS  (NB * NPTS)        // 262144 points

typedef unsigned short u16;
typedef unsigned int   u32;
typedef __attribute__((ext_vector_type(8))) short bf16x8;   // 8 bf16 = 4 VGPR
typedef __attribute__((ext_vector_type(4))) float f32x4;    // 16x16 MFMA C/D
typedef __attribute__((ext_vector_type(16))) float f32x16;  // 32x32 MFMA C/D

__device__ __forceinline__ u16 f2bf(float f) {
    u32 u = __float_as_uint(f);
    u = (u + 0x7fffu + ((u >> 16) & 1u)) >> 16;   // RNE
    return (u16)u;
}
__device__ __forceinline__ u32 pk2(float a, float b) {
    return (u32)f2bf(a) | ((u32)f2bf(b) << 16);
}
__device__ __forceinline__ f32x4 MFMA(bf16x8 a, bf16x8 b, f32x4 c) {
    return __builtin_amdgcn_mfma_f32_16x16x32_bf16(a, b, c, 0, 0, 0);
}
__device__ __forceinline__ f32x16 MFMA32(bf16x8 a, bf16x8 b, f32x16 c) {
    return __builtin_amdgcn_mfma_f32_32x32x16_bf16(a, b, c, 0, 0, 0);
}
template<int CTRL>
__device__ __forceinline__ float dpp_max(float v) {
    int t = __builtin_amdgcn_update_dpp(__float_as_int(v), __float_as_int(v),
                                        CTRL, 0xF, 0xF, false);
    return fmaxf(v, __int_as_float(t));
}
__device__ __forceinline__ float rowmax16(float v) {
    v = dpp_max<0xB1>(v);    // quad_perm xor1
    v = dpp_max<0x4E>(v);    // quad_perm xor2
    v = dpp_max<0x141>(v);   // row_half_mirror (xor4 on reduced)
    v = dpp_max<0x140>(v);   // row_mirror (xor8 on reduced)
    return v;
}
__device__ __forceinline__ void gload16(const void* g, void* l) {
    __builtin_amdgcn_global_load_lds(
        (const __attribute__((address_space(1))) unsigned int*)g,
        (__attribute__((address_space(3))) unsigned int*)l, 16, 0, 0);
}
template<int N> __device__ __forceinline__ void vwait() {
    if constexpr      (N == 0) asm volatile("s_waitcnt vmcnt(0)" ::: "memory");
    else if constexpr (N == 2) asm volatile("s_waitcnt vmcnt(2)" ::: "memory");
    else                       asm volatile("s_waitcnt vmcnt(4)" ::: "memory");
}
__device__ __forceinline__ void pin(bf16x8& v) { asm volatile("" : "+v"(v)); }

// Fragment conventions:
// 16x16x32 (verified r2-r7): A[row=l&15][k=(l>>4)*8+j]; B[k=(l>>4)*8+j][col=l15];
//   D[row=(l>>4)*4+r][col=l15].
// 32x32x16 (this round):     A[row=l&31][k=(l>>5)*8+j]; B[k=(l>>5)*8+j][col=l&31];
//   D[col=lane&31, row=(reg&3)+8*(reg>>2)+4*(lane>>5)]  [HW-verified m74/m101].
// Packed H4 (32-fmt): frag(pf32, kf16) at (pf32*16+kf16)*1024 + lane*16.
// Packed W (16-fmt):  frag(nf,kf) at (nf*KF+kf)*1024 + lane*16.

// ---------------- weight prepack: W2/3/4 16-fmt, W5 32-fmt ----------------
__global__ __launch_bounds__(256) void k_pack(const float* __restrict__ W2,
        const float* __restrict__ W3, const float* __restrict__ W4,
        const float* __restrict__ W5, u16* __restrict__ dst) {
    int idx = blockIdx.x * 256 + threadIdx.x;
    if (idx >= 720 * 64) return;
    int lane = idx & 63, fr = idx >> 6;
    const float* W; int C, o, c;
    if (fr < 208) {                       // W2/W3/W4: 16x16 A-frag layout
        int frl;
        if (fr < 16)      { W = W2; C = 64;  frl = fr;      }
        else if (fr < 80) { W = W3; C = 128; frl = fr - 16; }
        else              { W = W4; C = 256; frl = fr - 80; }
        int KF = C >> 5;
        int nf = frl / KF, kf = frl % KF;
        o = nf * 16 + (lane & 15);
        c = kf * 32 + (lane >> 4) * 8;
    } else {                              // W5: 32x32 A-frag layout (512 frags)
        int frl = fr - 208;
        int nf = frl >> 4, kf = frl & 15; // nf32 0..31, kf16 0..15
        W = W5; C = 256;
        o = nf * 32 + (lane & 31);
        c = kf * 16 + (lane >> 5) * 8;
    }
    const float* s = W + (size_t)o * C + c;
    u32 out[4];
    #pragma unroll
    for (int j = 0; j < 4; ++j) out[j] = pk2(s[2 * j], s[2 * j + 1]);
    *(uint4*)((char*)dst + (size_t)idx * 16) = make_uint4(out[0], out[1], out[2], out[3]);
}

// ---------------- K_FUSE: L1+L2+L3+L4, LDS intermediates (r7 winner) --------
// Only change vs r7: L4 stores H4 in 32x32 B-frag format for k_l5.
__global__ __launch_bounds__(512, 2) void k_fuse(const float* __restrict__ x,
        const float* __restrict__ W1, const float* __restrict__ b1,
        const u16* __restrict__ W2p, const float* __restrict__ b2,
        const u16* __restrict__ W3p, const float* __restrict__ b3,
        const u16* __restrict__ W4p, const float* __restrict__ b4,
        u16* __restrict__ H4, int pt0, int tpb) {
    __shared__ char regA[65536];               // H1 / H3
    __shared__ char regB[32768];               // H2
    const int tid = threadIdx.x, lane = tid & 63, w = tid >> 6;
    const int l15 = lane & 15, q = lane >> 4;
    const int qterm = ((q >> 1) * 16 + l15) * 16 + (q & 1) * 8;
    const int pl = tid & 127;                  // point-in-tile (L1)
    const int c4 = tid >> 7;                   // L1 channel quarter

    bf16x8 W2r[2], W3r[2][4], W4r[2][8];
    #pragma unroll
    for (int kf = 0; kf < 2; ++kf) {
        W2r[kf] = *(const bf16x8*)((const char*)W2p + (size_t)(w * 2 + kf) * 1024 + lane * 16);
        pin(W2r[kf]);
    }
    #pragma unroll
    for (int n = 0; n < 2; ++n)
        #pragma unroll
        for (int kf = 0; kf < 4; ++kf) {
            W3r[n][kf] = *(const bf16x8*)((const char*)W3p +
                           (size_t)((w * 2 + n) * 4 + kf) * 1024 + lane * 16);
            pin(W3r[n][kf]);
        }
    #pragma unroll
    for (int n = 0; n < 2; ++n)
        #pragma unroll
        for (int kf = 0; kf < 8; ++kf) {
            W4r[n][kf] = *(const bf16x8*)((const char*)W4p +
                           (size_t)((w * 2 + n) * 8 + kf) * 1024 + lane * 16);
            pin(W4r[n][kf]);
        }
    const f32x4 b2v = *(const f32x4*)(b2 + w * 16 + q * 4);
    f32x4 b3v[2], b4v[2];
    #pragma unroll
    for (int n = 0; n < 2; ++n) {
        b3v[n] = *(const f32x4*)(b3 + (w * 2 + n) * 16 + q * 4);
        b4v[n] = *(const f32x4*)(b4 + (w * 2 + n) * 16 + q * 4);
    }

    const int tile0 = blockIdx.x * tpb;
    float x0, x1, x2;
    {
        int ptg = pt0 + tile0 * 128 + pl;
        const float* xb = x + (size_t)(ptg >> 13) * 3 * NPTS + (ptg & 8191);
        x0 = xb[0]; x1 = xb[NPTS]; x2 = xb[2 * NPTS];
    }

    for (int it = 0; it < tpb; ++it) {
        const int tile = tile0 + it;
        // ---- L1: 3->64 (VALU) ----
        {
            u32 pk4[8];
            #pragma unroll
            for (int i = 0; i < 8; ++i) {
                int o0 = c4 * 16 + 2 * i, o1 = o0 + 1;
                float a0 = fmaxf(b1[o0] + W1[o0*3]*x0 + W1[o0*3+1]*x1 + W1[o0*3+2]*x2, 0.f);
                float a1 = fmaxf(b1[o1] + W1[o1*3]*x0 + W1[o1*3+1]*x1 + W1[o1*3+2]*x2, 0.f);
                pk4[i] = pk2(a0, a1);
            }
            char* rowp = regA + pl * 128;
            const int swz = (pl & 7) << 4;
            *(uint4*)(rowp + ((c4 * 32) ^ swz))      = make_uint4(pk4[0], pk4[1], pk4[2], pk4[3]);
            *(uint4*)(rowp + ((c4 * 32 + 16) ^ swz)) = make_uint4(pk4[4], pk4[5], pk4[6], pk4[7]);
        }
        __syncthreads();
        // ---- L2: 64->128 ----
        #pragma unroll
        for (int pf = 0; pf < 8; ++pf) {
            const int r2 = pf * 16 + l15;
            const char* rb = regA + r2 * 128;
            const int rsw = (r2 & 7) << 4;
            bf16x8 B0 = *(const bf16x8*)(rb + ((q * 16) ^ rsw));
            bf16x8 B1 = *(const bf16x8*)(rb + ((64 + q * 16) ^ rsw));
            f32x4 a = b2v;
            a = MFMA(W2r[0], B0, a);
            a = MFMA(W2r[1], B1, a);
            u32 d0 = pk2(fmaxf(a[0], 0.f), fmaxf(a[1], 0.f));
            u32 d1 = pk2(fmaxf(a[2], 0.f), fmaxf(a[3], 0.f));
            *(uint2*)(regB + (pf * 4 + (w >> 1)) * 1024 + (w & 1) * 512 + qterm)
                = make_uint2(d0, d1);
        }
        __syncthreads();
        // ---- L3: 128->256 ----
        #pragma unroll
        for (int pf = 0; pf < 8; ++pf) {
            bf16x8 B[4];
            #pragma unroll
            for (int kf = 0; kf < 4; ++kf)
                B[kf] = *(const bf16x8*)(regB + (pf * 4 + kf) * 1024 + lane * 16);
            f32x4 a0 = b3v[0], a1 = b3v[1];
            #pragma unroll
            for (int kf = 0; kf < 4; ++kf) {
                a0 = MFMA(W3r[0][kf], B[kf], a0);
                a1 = MFMA(W3r[1][kf], B[kf], a1);
            }
            char* db = regA + (pf * 8 + w) * 1024;
            *(uint2*)(db + qterm)       = make_uint2(pk2(fmaxf(a0[0],0.f), fmaxf(a0[1],0.f)),
                                                     pk2(fmaxf(a0[2],0.f), fmaxf(a0[3],0.f)));
            *(uint2*)(db + 512 + qterm) = make_uint2(pk2(fmaxf(a1[0],0.f), fmaxf(a1[1],0.f)),
                                                     pk2(fmaxf(a1[2],0.f), fmaxf(a1[3],0.f)));
        }
        __syncthreads();
        // ---- L4: 256->256, store H4 as 32x32 B-frags -----------------------
        // D lane (q,l15) holds ch {nf16*16 + 4q+r} of pt (pf,l15).
        // 32-frag coords: pf32 = tile*4+(pf>>1); kf16 = nf16;
        //   lane' = (q>>1)*32 + (pf&1)*16 + l15; byte = lane'*16 + (q&1)*8.
        #pragma unroll
        for (int pf = 0; pf < 8; ++pf) {
            bf16x8 B[8];
            #pragma unroll
            for (int kf = 0; kf < 8; ++kf)
                B[kf] = *(const bf16x8*)(regA + (pf * 8 + kf) * 1024 + lane * 16);
            f32x4 a0 = b4v[0], a1 = b4v[1];
            #pragma unroll
            for (int kf = 0; kf < 8; ++kf) {
                a0 = MFMA(W4r[0][kf], B[kf], a0);
                a1 = MFMA(W4r[1][kf], B[kf], a1);
            }
            const size_t pf32 = (size_t)tile * 4 + (pf >> 1);
            const int lterm = ((q >> 1) * 32 + (pf & 1) * 16 + l15) * 16 + (q & 1) * 8;
            char* d0p = (char*)H4 + (pf32 * 16 + (w * 2 + 0)) * 1024 + lterm;
            char* d1p = (char*)H4 + (pf32 * 16 + (w * 2 + 1)) * 1024 + lterm;
            *(uint2*)d0p = make_uint2(pk2(fmaxf(a0[0],0.f), fmaxf(a0[1],0.f)),
                                      pk2(fmaxf(a0[2],0.f), fmaxf(a0[3],0.f)));
            *(uint2*)d1p = make_uint2(pk2(fmaxf(a1[0],0.f), fmaxf(a1[1],0.f)),
                                      pk2(fmaxf(a1[2],0.f), fmaxf(a1[3],0.f)));
        }
        if (it + 1 < tpb) {
            int ptg = pt0 + (tile + 1) * 128 + pl;
            const float* xb = x + (size_t)(ptg >> 13) * 3 * NPTS + (ptg & 8191);
            x0 = xb[0]; x1 = xb[NPTS]; x2 = xb[2 * NPTS];
        }
        __syncthreads();
    }
}

// ---------------- K_L5 v8: 256->1024 + max-pool, 32x32x16 MFMA --------------
// r4's proven pipeline (3-buf, vwait<2>, 1 barrier/step), 8 waves, ZSL=2.
// Wave owns 2 nf32 (64 z); step = 1 pf32 (32 pts, 16 KB staged).
__global__ __launch_bounds__(512, 2) void k_l5(const u16* __restrict__ Hin,
        const u16* __restrict__ Wp, const float* __restrict__ b5,
        float* __restrict__ parts, int slot0) {
    constexpr int BUFB = 16384;                // 1 pf32 x 16 kf16 x 1KB
    constexpr int STEPS = 32;                  // 32 pf32 = 1024 pts
    __shared__ char ldsB[3 * BUFB];            // 48 KB
    const int tid = threadIdx.x, lane = tid & 63, w = tid >> 6;
    const int zsl = blockIdx.x & 1, pgrp = blockIdx.x >> 1;
    const int pfb = pgrp * 32;                 // pf32 base

    bf16x8 W[2][16];                           // 2 nf32 x 16 kf16 (128 regs)
    {
        const char* wb = (const char*)Wp + (size_t)(zsl * 16 + w * 2) * 16 * 1024;
        #pragma unroll
        for (int n = 0; n < 2; ++n)
            #pragma unroll
            for (int kf = 0; kf < 16; ++kf)
                W[n][kf] = *(const bf16x8*)(wb + (size_t)(n * 16 + kf) * 1024 + lane * 16);
    }
    f32x16 vmax0, vmax1;
    #pragma unroll
    for (int r = 0; r < 16; ++r) { vmax0[r] = -3.402823466e38f; vmax1[r] = -3.402823466e38f; }

    auto stage = [&](int t, int bsel) {        // 16 KB, 2 KB per wave
        const char* g = (const char*)Hin + (size_t)(pfb + t) * 16384 + w * 2048 + lane * 16;
        char* l = ldsB + bsel * BUFB + w * 2048;
        gload16(g, l);
        gload16(g + 1024, l + 1024);
    };
    stage(0, 0);
    stage(1, 1);
    int bufc = 0;
    for (int t = 0; t < STEPS; ++t) {
        if (t + 1 < STEPS) vwait<2>(); else vwait<0>();
        __builtin_amdgcn_sched_barrier(0);
        __builtin_amdgcn_s_barrier();
        const char* bp = ldsB + bufc * BUFB;
        f32x16 acc0, acc1;
        #pragma unroll
        for (int r = 0; r < 16; ++r) { acc0[r] = 0.f; acc1[r] = 0.f; }
        #pragma unroll
        for (int kf = 0; kf < 16; ++kf) {
            bf16x8 B = *(const bf16x8*)(bp + (size_t)kf * 1024 + lane * 16);
            acc0 = MFMA32(W[0][kf], B, acc0);
            acc1 = MFMA32(W[1][kf], B, acc1);
        }
        #pragma unroll
        for (int r = 0; r < 16; ++r) {
            vmax0[r] = fmaxf(vmax0[r], acc0[r]);
            vmax1[r] = fmaxf(vmax1[r], acc1[r]);
        }
        if (t + 2 < STEPS) {
            int b2 = bufc + 2; if (b2 >= 3) b2 -= 3;
            stage(t + 2, b2);
        }
        ++bufc; if (bufc == 3) bufc = 0;
    }
    // Reduce over the 32 point-columns (col = lane&31; rows split by lane>>5),
    // then one write per lane: (n,r) = ((lane&31)>>4, lane&15).
    const int zb = zsl * 512 + w * 64;
    float mywr = -3.402823466e38f;
    #pragma unroll
    for (int r = 0; r < 16; ++r) {
        float m0 = rowmax16(vmax0[r]);
        m0 = fmaxf(m0, __shfl_xor(m0, 16, 64));
        if ((lane & 31) == r) mywr = m0;           // n=0
        float m1 = rowmax16(vmax1[r]);
        m1 = fmaxf(m1, __shfl_xor(m1, 16, 64));
        if ((lane & 31) == 16 + r) mywr = m1;      // n=1
    }
    const int r_ = lane & 15;
    const int zloc = zb + ((lane >> 4) & 1) * 32 + (r_ & 3) + 8 * (r_ >> 2) + 4 * (lane >> 5);
    parts[(size_t)(slot0 + pgrp) * 1024 + zloc] = mywr + b5[zloc];
}

// ---------------- final reduce: slot = 1024-pt group; 8 slots per batch ------
__global__ __launch_bounds__(256) void k_red(const float* __restrict__ parts,
                                             float* __restrict__ out) {
    int i = blockIdx.x * 256 + threadIdx.x;    // 32768
    int b = i >> 10, z = i & 1023;
    float m = -3.402823466e38f;
    #pragma unroll
    for (int s = 0; s < 8; ++s)
        m = fmaxf(m, parts[((size_t)b * 8 + s) * 1024 + z]);
    out[i] = m;
}

extern "C" void kernel_launch(void* const* d_in, const int* in_sizes, int n_in,
                              void* d_out, int out_size, void* d_ws, size_t ws_size,
                              hipStream_t stream) {
    const float* x  = (const float*)d_in[0];
    const float* W1 = (const float*)d_in[1]; const float* b1 = (const float*)d_in[2];
    const float* W2 = (const float*)d_in[3]; const float* b2 = (const float*)d_in[4];
    const float* W3 = (const float*)d_in[5]; const float* b3 = (const float*)d_in[6];
    const float* W4 = (const float*)d_in[7]; const float* b4 = (const float*)d_in[8];
    const float* W5 = (const float*)d_in[9]; const float* b5 = (const float*)d_in[10];

    u16* wsW = (u16*)d_ws;
    const u16* W2p = (const u16*)((char*)d_ws + 0);
    const u16* W3p = (const u16*)((char*)d_ws + 16 * 1024);
    const u16* W4p = (const u16*)((char*)d_ws + 80 * 1024);
    const u16* W5p = (const u16*)((char*)d_ws + 208 * 1024);
    float* parts   = (float*)((char*)d_ws + 786432);           // 256 slots x 4KB
    char* Hbase    = (char*)d_ws + 786432 + 2097152;

    int NCH = 1;
    while (NCH < 32) {
        size_t npc = (size_t)TOTPTS / NCH;
        if (786432 + 2097152 + npc * 512 <= ws_size) break;
        NCH *= 2;
    }
    const size_t npts_c = (size_t)TOTPTS / NCH;
    char* HB = Hbase;                           // H4 chunk buffer (512 B/pt)

    k_pack<<<dim3(180), dim3(256), 0, stream>>>(W2, W3, W4, W5, wsW);

    const int ntiles = (int)(npts_c / 128);     // k_fuse tiles per chunk
    const int nblk   = (ntiles >= 256) ? 256 : ntiles;
    const int tpb    = ntiles / nblk;
    for (int c = 0; c < NCH; ++c) {
        int pt0   = (int)(c * npts_c);
        int slot0 = (int)((c * npts_c) >> 10);  // 1024-pt groups
        k_fuse<<<dim3(nblk), dim3(512), 0, stream>>>(
            x, W1, b1, W2p, b2, W3p, b3, W4p, b4, (u16*)HB, pt0, tpb);
        k_l5<<<dim3(2 * (int)(npts_c / 1024)), dim3(512), 0, stream>>>(
            (const u16*)HB, W5p, b5, parts, slot0);
    }
    k_red<<<dim3(128), dim3(256), 0, stream>>>(parts, (float*)d_out);
}

// Round 9
// 165.167 us; speedup vs baseline: 1.0903x; 1.0903x over previous
//
#include <hip/hip_runtime.h>
#include <math.h>

// ---------------- problem constants ----------------
#define NB      32
#define NPTS    8192
#define TOTPTS  (NB * NPTS)        // 262144 points

typedef unsigned short u16;
typedef unsigned int   u32;
typedef __attribute__((ext_vector_type(8))) short bf16x8;  // 8 bf16 = 4 VGPR
typedef __attribute__((ext_vector_type(4))) float f32x4;   // MFMA C/D

__device__ __forceinline__ u16 f2bf(float f) {
    u32 u = __float_as_uint(f);
    u = (u + 0x7fffu + ((u >> 16) & 1u)) >> 16;   // RNE
    return (u16)u;
}
__device__ __forceinline__ u32 pk2(float a, float b) {
    return (u32)f2bf(a) | ((u32)f2bf(b) << 16);
}
__device__ __forceinline__ f32x4 MFMA(bf16x8 a, bf16x8 b, f32x4 c) {
    return __builtin_amdgcn_mfma_f32_16x16x32_bf16(a, b, c, 0, 0, 0);
}
template<int CTRL>
__device__ __forceinline__ float dpp_max(float v) {
    int t = __builtin_amdgcn_update_dpp(__float_as_int(v), __float_as_int(v),
                                        CTRL, 0xF, 0xF, false);
    return fmaxf(v, __int_as_float(t));
}
__device__ __forceinline__ float rowmax16(float v) {
    v = dpp_max<0xB1>(v);    // quad_perm xor1
    v = dpp_max<0x4E>(v);    // quad_perm xor2
    v = dpp_max<0x141>(v);   // row_half_mirror (xor4 on reduced)
    v = dpp_max<0x140>(v);   // row_mirror (xor8 on reduced)
    return v;
}
__device__ __forceinline__ void gload16(const void* g, void* l) {
    __builtin_amdgcn_global_load_lds(
        (const __attribute__((address_space(1))) unsigned int*)g,
        (__attribute__((address_space(3))) unsigned int*)l, 16, 0, 0);
}
template<int N> __device__ __forceinline__ void vwait() {
    if constexpr (N == 0) asm volatile("s_waitcnt vmcnt(0)" ::: "memory");
    else                  asm volatile("s_waitcnt vmcnt(4)" ::: "memory");
}
__device__ __forceinline__ void pin(bf16x8& v) { asm volatile("" : "+v"(v)); }

// Fragment conventions (mfma_f32_16x16x32_bf16), verified rounds 2-8:
//   A: lane holds A[row=l&15][k=(l>>4)*8+j]  -> W[o][c] frag
//   B: lane holds B[k=(l>>4)*8+j][col=l&15]  -> H^T frag (col = point)
//   D: lane holds D[row=(l>>4)*4+r][col=l&15]
// Packed H: frag(pf,kf) at byte (pf*KF+kf)*1024 + lane*16.
// Packed W: frag(nf,kf) at byte (nf*KF+kf)*1024 + lane*16.

// ---------------- weight prepack (r7 verbatim) ----------------
__global__ __launch_bounds__(256) void k_pack(const float* __restrict__ W2,
        const float* __restrict__ W3, const float* __restrict__ W4,
        const float* __restrict__ W5, u16* __restrict__ dst) {
    int idx = blockIdx.x * 256 + threadIdx.x;
    if (idx >= 720 * 64) return;
    int lane = idx & 63, fr = idx >> 6;
    const float* W; int C, frl;
    if (fr < 16)       { W = W2; C = 64;  frl = fr;       }
    else if (fr < 80)  { W = W3; C = 128; frl = fr - 16;  }
    else if (fr < 208) { W = W4; C = 256; frl = fr - 80;  }
    else               { W = W5; C = 256; frl = fr - 208; }
    int KF = C >> 5;
    int nf = frl / KF, kf = frl % KF;
    int o = nf * 16 + (lane & 15), c = kf * 32 + (lane >> 4) * 8;
    const float* s = W + (size_t)o * C + c;
    u32 out[4];
    #pragma unroll
    for (int j = 0; j < 4; ++j) out[j] = pk2(s[2 * j], s[2 * j + 1]);
    *(uint4*)((char*)dst + (size_t)idx * 16) = make_uint4(out[0], out[1], out[2], out[3]);
}

// ---------------- K_FUSE: L1+L2+L3+L4, LDS intermediates (r7 verbatim) ------
__global__ __launch_bounds__(512, 2) void k_fuse(const float* __restrict__ x,
        const float* __restrict__ W1, const float* __restrict__ b1,
        const u16* __restrict__ W2p, const float* __restrict__ b2,
        const u16* __restrict__ W3p, const float* __restrict__ b3,
        const u16* __restrict__ W4p, const float* __restrict__ b4,
        u16* __restrict__ H4, int pt0, int tpb) {
    __shared__ char regA[65536];               // H1 / H3
    __shared__ char regB[32768];               // H2
    const int tid = threadIdx.x, lane = tid & 63, w = tid >> 6;
    const int l15 = lane & 15, q = lane >> 4;
    const int qterm = ((q >> 1) * 16 + l15) * 16 + (q & 1) * 8;
    const int pl = tid & 127;                  // point-in-tile (L1)
    const int c4 = tid >> 7;                   // L1 channel quarter

    bf16x8 W2r[2], W3r[2][4], W4r[2][8];
    #pragma unroll
    for (int kf = 0; kf < 2; ++kf) {
        W2r[kf] = *(const bf16x8*)((const char*)W2p + (size_t)(w * 2 + kf) * 1024 + lane * 16);
        pin(W2r[kf]);
    }
    #pragma unroll
    for (int n = 0; n < 2; ++n)
        #pragma unroll
        for (int kf = 0; kf < 4; ++kf) {
            W3r[n][kf] = *(const bf16x8*)((const char*)W3p +
                           (size_t)((w * 2 + n) * 4 + kf) * 1024 + lane * 16);
            pin(W3r[n][kf]);
        }
    #pragma unroll
    for (int n = 0; n < 2; ++n)
        #pragma unroll
        for (int kf = 0; kf < 8; ++kf) {
            W4r[n][kf] = *(const bf16x8*)((const char*)W4p +
                           (size_t)((w * 2 + n) * 8 + kf) * 1024 + lane * 16);
            pin(W4r[n][kf]);
        }
    const f32x4 b2v = *(const f32x4*)(b2 + w * 16 + q * 4);
    f32x4 b3v[2], b4v[2];
    #pragma unroll
    for (int n = 0; n < 2; ++n) {
        b3v[n] = *(const f32x4*)(b3 + (w * 2 + n) * 16 + q * 4);
        b4v[n] = *(const f32x4*)(b4 + (w * 2 + n) * 16 + q * 4);
    }

    const int tile0 = blockIdx.x * tpb;
    float x0, x1, x2;
    {
        int ptg = pt0 + tile0 * 128 + pl;
        const float* xb = x + (size_t)(ptg >> 13) * 3 * NPTS + (ptg & 8191);
        x0 = xb[0]; x1 = xb[NPTS]; x2 = xb[2 * NPTS];
    }

    for (int it = 0; it < tpb; ++it) {
        const int tile = tile0 + it;
        // ---- L1: 3->64 (VALU) ----
        {
            u32 pk4[8];
            #pragma unroll
            for (int i = 0; i < 8; ++i) {
                int o0 = c4 * 16 + 2 * i, o1 = o0 + 1;
                float a0 = fmaxf(b1[o0] + W1[o0*3]*x0 + W1[o0*3+1]*x1 + W1[o0*3+2]*x2, 0.f);
                float a1 = fmaxf(b1[o1] + W1[o1*3]*x0 + W1[o1*3+1]*x1 + W1[o1*3+2]*x2, 0.f);
                pk4[i] = pk2(a0, a1);
            }
            char* rowp = regA + pl * 128;
            const int swz = (pl & 7) << 4;
            *(uint4*)(rowp + ((c4 * 32) ^ swz))      = make_uint4(pk4[0], pk4[1], pk4[2], pk4[3]);
            *(uint4*)(rowp + ((c4 * 32 + 16) ^ swz)) = make_uint4(pk4[4], pk4[5], pk4[6], pk4[7]);
        }
        __syncthreads();
        // ---- L2: 64->128 ----
        #pragma unroll
        for (int pf = 0; pf < 8; ++pf) {
            const int r2 = pf * 16 + l15;
            const char* rb = regA + r2 * 128;
            const int rsw = (r2 & 7) << 4;
            bf16x8 B0 = *(const bf16x8*)(rb + ((q * 16) ^ rsw));
            bf16x8 B1 = *(const bf16x8*)(rb + ((64 + q * 16) ^ rsw));
            f32x4 a = b2v;
            a = MFMA(W2r[0], B0, a);
            a = MFMA(W2r[1], B1, a);
            u32 d0 = pk2(fmaxf(a[0], 0.f), fmaxf(a[1], 0.f));
            u32 d1 = pk2(fmaxf(a[2], 0.f), fmaxf(a[3], 0.f));
            *(uint2*)(regB + (pf * 4 + (w >> 1)) * 1024 + (w & 1) * 512 + qterm)
                = make_uint2(d0, d1);
        }
        __syncthreads();
        // ---- L3: 128->256 ----
        #pragma unroll
        for (int pf = 0; pf < 8; ++pf) {
            bf16x8 B[4];
            #pragma unroll
            for (int kf = 0; kf < 4; ++kf)
                B[kf] = *(const bf16x8*)(regB + (pf * 4 + kf) * 1024 + lane * 16);
            f32x4 a0 = b3v[0], a1 = b3v[1];
            #pragma unroll
            for (int kf = 0; kf < 4; ++kf) {
                a0 = MFMA(W3r[0][kf], B[kf], a0);
                a1 = MFMA(W3r[1][kf], B[kf], a1);
            }
            char* db = regA + (pf * 8 + w) * 1024;
            *(uint2*)(db + qterm)       = make_uint2(pk2(fmaxf(a0[0],0.f), fmaxf(a0[1],0.f)),
                                                     pk2(fmaxf(a0[2],0.f), fmaxf(a0[3],0.f)));
            *(uint2*)(db + 512 + qterm) = make_uint2(pk2(fmaxf(a1[0],0.f), fmaxf(a1[1],0.f)),
                                                     pk2(fmaxf(a1[2],0.f), fmaxf(a1[3],0.f)));
        }
        __syncthreads();
        // ---- L4: 256->256, store H4 frags (16-fmt) to global ----
        #pragma unroll
        for (int pf = 0; pf < 8; ++pf) {
            bf16x8 B[8];
            #pragma unroll
            for (int kf = 0; kf < 8; ++kf)
                B[kf] = *(const bf16x8*)(regA + (pf * 8 + kf) * 1024 + lane * 16);
            f32x4 a0 = b4v[0], a1 = b4v[1];
            #pragma unroll
            for (int kf = 0; kf < 8; ++kf) {
                a0 = MFMA(W4r[0][kf], B[kf], a0);
                a1 = MFMA(W4r[1][kf], B[kf], a1);
            }
            char* db = (char*)H4 + ((size_t)(tile * 8 + pf) * 8 + w) * 1024;
            *(uint2*)(db + qterm)       = make_uint2(pk2(fmaxf(a0[0],0.f), fmaxf(a0[1],0.f)),
                                                     pk2(fmaxf(a0[2],0.f), fmaxf(a0[3],0.f)));
            *(uint2*)(db + 512 + qterm) = make_uint2(pk2(fmaxf(a1[0],0.f), fmaxf(a1[1],0.f)),
                                                     pk2(fmaxf(a1[2],0.f), fmaxf(a1[3],0.f)));
        }
        if (it + 1 < tpb) {
            int ptg = pt0 + (tile + 1) * 128 + pl;
            const float* xb = x + (size_t)(ptg >> 13) * 3 * NPTS + (ptg & 8191);
            x0 = xb[0]; x1 = xb[NPTS]; x2 = xb[2 * NPTS];
        }
        __syncthreads();
    }
}

// ---------------- K_L5 v9: 16x16 MFMA, 4-pf steps, 2-buffer DMA --------------
// Block: 8 waves = 32 nf (zsl half of 1024 z); 64 pf per block, 4 pf/step.
// Order per step: vwait(own stage(t)) -> barrier (publishes ALL waves' slices)
// -> issue stage(t+1) into the buffer whose readers just passed the barrier
// -> compute(t) (hides stage(t+1) latency under ~5k cyc of MFMA).
__global__ __launch_bounds__(512, 2) void k_l5(const u16* __restrict__ Hin,
        const u16* __restrict__ Wp, const float* __restrict__ b5,
        float* __restrict__ parts, int slot0) {
    constexpr int BUFB = 32768;                // 4 pf x 8 kf x 1KB
    constexpr int STEPS = 16;                  // 64 pf
    __shared__ char ldsB[2 * BUFB];            // 64 KB
    const int tid = threadIdx.x, lane = tid & 63, w = tid >> 6;
    const int l15 = lane & 15, q = lane >> 4;
    const int zsl = blockIdx.x & 1, pgrp = blockIdx.x >> 1;
    const int pfb = pgrp * 64;

    bf16x8 W[4][8];                            // 4 nf x 8 kf (AGPR-resident, r4)
    {
        const char* wb = (const char*)Wp + (size_t)(zsl * 32 + w * 4) * 8 * 1024;
        #pragma unroll
        for (int nf = 0; nf < 4; ++nf)
            #pragma unroll
            for (int kf = 0; kf < 8; ++kf)
                W[nf][kf] = *(const bf16x8*)(wb + (size_t)(nf * 8 + kf) * 1024 + lane * 16);
    }
    f32x4 vmax[4];
    #pragma unroll
    for (int nf = 0; nf < 4; ++nf)
        #pragma unroll
        for (int r = 0; r < 4; ++r) vmax[nf][r] = -3.402823466e38f;

    auto stage = [&](int t, int bsel) {        // 32 KB total, 4 KB per wave
        const char* g = (const char*)Hin + ((size_t)(pfb + t * 4) * 8) * 1024
                        + w * 4096 + lane * 16;
        char* l = ldsB + bsel * BUFB + w * 4096;
        gload16(g,        l);
        gload16(g + 1024, l + 1024);
        gload16(g + 2048, l + 2048);
        gload16(g + 3072, l + 3072);
    };
    stage(0, 0);
    for (int t = 0; t < STEPS; ++t) {
        vwait<0>();                            // own stage(t) landed
        __builtin_amdgcn_sched_barrier(0);
        __builtin_amdgcn_s_barrier();          // all waves' slices visible
        if (t + 1 < STEPS) stage(t + 1, (t + 1) & 1);   // buf readers passed bar
        const char* bp = ldsB + (t & 1) * BUFB;
        #pragma unroll
        for (int p = 0; p < 4; ++p) {
            f32x4 acc[4];
            #pragma unroll
            for (int nf = 0; nf < 4; ++nf)
                #pragma unroll
                for (int r = 0; r < 4; ++r) acc[nf][r] = 0.f;
            #pragma unroll
            for (int kf = 0; kf < 8; ++kf) {
                bf16x8 B = *(const bf16x8*)(bp + (size_t)(p * 8 + kf) * 1024 + lane * 16);
                #pragma unroll
                for (int nf = 0; nf < 4; ++nf) acc[nf] = MFMA(W[nf][kf], B, acc[nf]);
            }
            #pragma unroll
            for (int nf = 0; nf < 4; ++nf)
                #pragma unroll
                for (int r = 0; r < 4; ++r)
                    vmax[nf][r] = fmaxf(vmax[nf][r], acc[nf][r]);
        }
    }
    const int zb = zsl * 512 + w * 64;
    float* dst = parts + (size_t)(slot0 + pgrp) * 1024 + zb;
    #pragma unroll
    for (int nf = 0; nf < 4; ++nf)
        #pragma unroll
        for (int r = 0; r < 4; ++r) {
            float m = rowmax16(vmax[nf][r]);
            if (l15 == nf * 4 + r) {
                int zi = nf * 16 + q * 4 + r;
                dst[zi] = m + b5[zb + zi];
            }
        }
}

// ---------------- final reduce: slot = 1024-pt group; 8 slots per batch ------
__global__ __launch_bounds__(256) void k_red(const float* __restrict__ parts,
                                             float* __restrict__ out) {
    int i = blockIdx.x * 256 + threadIdx.x;    // 32768
    int b = i >> 10, z = i & 1023;
    float m = -3.402823466e38f;
    #pragma unroll
    for (int s = 0; s < 8; ++s)
        m = fmaxf(m, parts[((size_t)b * 8 + s) * 1024 + z]);
    out[i] = m;
}

extern "C" void kernel_launch(void* const* d_in, const int* in_sizes, int n_in,
                              void* d_out, int out_size, void* d_ws, size_t ws_size,
                              hipStream_t stream) {
    const float* x  = (const float*)d_in[0];
    const float* W1 = (const float*)d_in[1]; const float* b1 = (const float*)d_in[2];
    const float* W2 = (const float*)d_in[3]; const float* b2 = (const float*)d_in[4];
    const float* W3 = (const float*)d_in[5]; const float* b3 = (const float*)d_in[6];
    const float* W4 = (const float*)d_in[7]; const float* b4 = (const float*)d_in[8];
    const float* W5 = (const float*)d_in[9]; const float* b5 = (const float*)d_in[10];

    u16* wsW = (u16*)d_ws;
    const u16* W2p = (const u16*)((char*)d_ws + 0);
    const u16* W3p = (const u16*)((char*)d_ws + 16 * 1024);
    const u16* W4p = (const u16*)((char*)d_ws + 80 * 1024);
    const u16* W5p = (const u16*)((char*)d_ws + 208 * 1024);
    float* parts   = (float*)((char*)d_ws + 786432);           // 256 slots x 4KB
    char* Hbase    = (char*)d_ws + 786432 + 2097152;

    int NCH = 1;
    while (NCH < 32) {
        size_t npc = (size_t)TOTPTS / NCH;
        if (786432 + 2097152 + npc * 512 <= ws_size) break;
        NCH *= 2;
    }
    const size_t npts_c = (size_t)TOTPTS / NCH;
    char* HB = Hbase;                           // H4 chunk buffer (512 B/pt)

    k_pack<<<dim3(180), dim3(256), 0, stream>>>(W2, W3, W4, W5, wsW);

    const int ntiles = (int)(npts_c / 128);     // k_fuse tiles per chunk
    const int nblk   = (ntiles >= 256) ? 256 : ntiles;
    const int tpb    = ntiles / nblk;
    for (int c = 0; c < NCH; ++c) {
        int pt0   = (int)(c * npts_c);
        int slot0 = (int)((c * npts_c) >> 10);  // 1024-pt groups
        k_fuse<<<dim3(nblk), dim3(512), 0, stream>>>(
            x, W1, b1, W2p, b2, W3p, b3, W4p, b4, (u16*)HB, pt0, tpb);
        k_l5<<<dim3(2 * (int)(npts_c / 1024)), dim3(512), 0, stream>>>(
            (const u16*)HB, W5p, b5, parts, slot0);
    }
    k_red<<<dim3(128), dim3(256), 0, stream>>>(parts, (float*)d_out);
}